// Round 5
// baseline (223.460 us; speedup 1.0000x reference)
//
#include <hip/hip_runtime.h>
#include <hip/hip_cooperative_groups.h>
#include <stdint.h>

namespace cg = cooperative_groups;

#define G_SHOWERS 8192
#define NBINS (2 * G_SHOWERS)  // bin = kind*8192 + sid; kind: 0=hits, 1=tracks

typedef float f32x4 __attribute__((ext_vector_type(4)));

// ws layout:
//   [0, nb*64K)    : partial slabs u32/f32 [nb][NBINS] (bmax pass, then esum pass)
//   [+0,   +64K)   : bmax_g u32[NBINS]
//   [+64K, +128K)  : corr_g u32[NBINS]
//   [+128K,+384K)  : table  f32[G][8]
//   [+384K, ...)   : binbuf u16[n] (optional, if ws large enough)

// ============================ fused cooperative kernel ======================
__global__ __launch_bounds__(1024, 1) void fused_kernel(
    const int* __restrict__ sid, const int* __restrict__ hitid,
    const float* __restrict__ energy, const float* __restrict__ beta,
    const float* __restrict__ corr, unsigned* __restrict__ partial,
    unsigned* __restrict__ bmax_g, unsigned* __restrict__ corr_g,
    float* __restrict__ table, unsigned short* __restrict__ binbuf,
    float* __restrict__ out, int n, int nbSlabs) {
    cg::grid_group grid = cg::this_grid();
    __shared__ unsigned smem_u[NBINS];  // 64 KB, reused each phase

    const int tid = threadIdx.x;
    const int gtid = blockIdx.x * 1024 + tid;
    const int gstride = gridDim.x * 1024;
    const int nv = n >> 2;
    const int lane = tid & 63;
    const int q = tid >> 6;  // 0..15

    // ---------------- Phase A: per-block beta-max partials + bin stash ------
    for (int i = tid; i < NBINS; i += 1024) smem_u[i] = 0u;
    for (int i = gtid; i < NBINS; i += gstride) corr_g[i] = 0u;
    __syncthreads();

    for (int i = gtid; i < nv; i += gstride) {
        int4   s4 = reinterpret_cast<const int4*>(sid)[i];
        int4   h4 = reinterpret_cast<const int4*>(hitid)[i];
        float4 b4 = reinterpret_cast<const float4*>(beta)[i];
        const int* sp = (const int*)&s4;
        const int* hp = (const int*)&h4;
        const float* bp = (const float*)&b4;
        ushort4 bv;
        unsigned short* bvp = (unsigned short*)&bv;
        #pragma unroll
        for (int j = 0; j < 4; ++j) {
            int bin = (hp[j] != 0 ? G_SHOWERS : 0) + sp[j];
            bvp[j] = (unsigned short)bin;
            atomicMax(&smem_u[bin], __float_as_uint(bp[j]));
        }
        if (binbuf) reinterpret_cast<ushort4*>(binbuf)[i] = bv;
    }
    for (int i = nv * 4 + gtid; i < n; i += gstride) {
        int bin = (hitid[i] != 0 ? G_SHOWERS : 0) + sid[i];
        atomicMax(&smem_u[bin], __float_as_uint(beta[i]));
        if (binbuf) binbuf[i] = (unsigned short)bin;
    }

    __syncthreads();
    {
        unsigned* outp = partial + (size_t)blockIdx.x * NBINS;
        for (int i = tid; i < NBINS; i += 1024) outp[i] = smem_u[i];
    }
    grid.sync();

    // ---------------- Phase B: reduce bmax partials -> bmax_g ---------------
    {
        const int ngroups = NBINS / 64;  // 256
        const int iters = (ngroups + gridDim.x - 1) / gridDim.x;
        for (int it = 0; it < iters; ++it) {
            int gb = it * gridDim.x + blockIdx.x;
            bool active = gb < ngroups;
            int bin = gb * 64 + lane;
            unsigned m = 0u;
            if (active) {
                for (int s = q; s < nbSlabs; s += 16)
                    m = max(m, partial[(size_t)s * NBINS + bin]);
            }
            __syncthreads();
            smem_u[q * 64 + lane] = m;
            __syncthreads();
            if (q == 0 && active) {
                #pragma unroll
                for (int j = 1; j < 16; ++j) m = max(m, smem_u[j * 64 + lane]);
                bmax_g[bin] = m;
            }
        }
    }
    grid.sync();

    // ---------------- Phase C: esum partials + sparse corr atomicMax --------
    {
        float* es = (float*)smem_u;
        for (int i = tid; i < NBINS; i += 1024) es[i] = 0.0f;
        __syncthreads();

        for (int i = gtid; i < nv; i += gstride) {
            float4 e4 = reinterpret_cast<const float4*>(energy)[i];
            float4 b4 = reinterpret_cast<const float4*>(beta)[i];
            float4 c4 = reinterpret_cast<const float4*>(corr)[i];
            const float* ep = (const float*)&e4;
            const float* bp = (const float*)&b4;
            const float* cp = (const float*)&c4;
            int bins[4];
            if (binbuf) {
                ushort4 bv = reinterpret_cast<const ushort4*>(binbuf)[i];
                bins[0] = bv.x; bins[1] = bv.y; bins[2] = bv.z; bins[3] = bv.w;
            } else {
                int4 s4 = reinterpret_cast<const int4*>(sid)[i];
                int4 h4 = reinterpret_cast<const int4*>(hitid)[i];
                const int* sp = (const int*)&s4;
                const int* hp = (const int*)&h4;
                #pragma unroll
                for (int j = 0; j < 4; ++j)
                    bins[j] = (hp[j] != 0 ? G_SHOWERS : 0) + sp[j];
            }
            #pragma unroll
            for (int j = 0; j < 4; ++j) {
                atomicAdd(&es[bins[j]], ep[j]);
                if (__float_as_uint(bp[j]) == bmax_g[bins[j]]) {
                    atomicMax(&corr_g[bins[j]], __float_as_uint(cp[j]));
                }
            }
        }
        for (int i = nv * 4 + gtid; i < n; i += gstride) {
            int bin = (hitid[i] != 0 ? G_SHOWERS : 0) + sid[i];
            atomicAdd(&es[bin], energy[i]);
            if (__float_as_uint(beta[i]) == bmax_g[bin]) {
                atomicMax(&corr_g[bin], __float_as_uint(corr[i]));
            }
        }

        __syncthreads();
        float* outp = (float*)(partial + (size_t)blockIdx.x * NBINS);
        for (int i = tid; i < NBINS; i += 1024) outp[i] = es[i];
    }
    grid.sync();

    // ---------------- Phase D: reduce esum + build table --------------------
    {
        const float* pe = (const float*)partial;
        float* rh = (float*)smem_u;          // [16][64]
        float* rt = ((float*)smem_u) + 1024; // [16][64]
        const int ngroups = G_SHOWERS / 64;  // 128
        const int iters = (ngroups + gridDim.x - 1) / gridDim.x;
        for (int it = 0; it < iters; ++it) {
            int gb = it * gridDim.x + blockIdx.x;
            bool active = gb < ngroups;
            int g = gb * 64 + lane;
            float ah = 0.0f, at = 0.0f;
            if (active) {
                for (int s = q; s < nbSlabs; s += 16) {
                    const float* p = pe + (size_t)s * NBINS;
                    ah += p[g];
                    at += p[G_SHOWERS + g];
                }
            }
            __syncthreads();
            rh[q * 64 + lane] = ah;
            rt[q * 64 + lane] = at;
            __syncthreads();
            if (q == 0 && active) {
                #pragma unroll
                for (int j = 1; j < 16; ++j) {
                    ah += rh[j * 64 + lane];
                    at += rt[j * 64 + lane];
                }
                float corr_hit = __uint_as_float(corr_g[g]);
                float corr_trk = __uint_as_float(corr_g[G_SHOWERS + g]);
                float cor_hit = corr_hit * ah;
                float cor_trk = corr_trk * at;
                float4 lo, hi;
                lo.x = at;
                lo.y = cor_trk;
                lo.z = ah;
                lo.w = cor_hit;
                hi.x = (at != 0.0f) ? at : ah;
                hi.y = (cor_trk != 0.0f) ? cor_trk : cor_hit;
                hi.z = (ah != 0.0f) ? ah : at;
                hi.w = (cor_hit != 0.0f) ? cor_hit : cor_trk;
                reinterpret_cast<float4*>(table)[2 * g]     = lo;
                reinterpret_cast<float4*>(table)[2 * g + 1] = hi;
            }
        }
    }
    grid.sync();

    // ---------------- Phase E: broadcast gather to 8 planes -----------------
    {
        const f32x4* tbl = reinterpret_cast<const f32x4*>(table);
        for (int i = gtid; i < nv; i += gstride) {
            int s0, s1, s2, s3;
            if (binbuf) {
                ushort4 bv = reinterpret_cast<const ushort4*>(binbuf)[i];
                s0 = bv.x & (G_SHOWERS - 1); s1 = bv.y & (G_SHOWERS - 1);
                s2 = bv.z & (G_SHOWERS - 1); s3 = bv.w & (G_SHOWERS - 1);
            } else {
                int4 s4 = reinterpret_cast<const int4*>(sid)[i];
                s0 = s4.x; s1 = s4.y; s2 = s4.z; s3 = s4.w;
            }
            f32x4 ax = tbl[2 * s0], bx = tbl[2 * s0 + 1];
            f32x4 ay = tbl[2 * s1], by = tbl[2 * s1 + 1];
            f32x4 az = tbl[2 * s2], bz = tbl[2 * s2 + 1];
            f32x4 aw = tbl[2 * s3], bw = tbl[2 * s3 + 1];

            f32x4 p;
            p.x = ax.x; p.y = ay.x; p.z = az.x; p.w = aw.x;
            __builtin_nontemporal_store(p, reinterpret_cast<f32x4*>(out + 0ll * n) + i);
            p.x = ax.y; p.y = ay.y; p.z = az.y; p.w = aw.y;
            __builtin_nontemporal_store(p, reinterpret_cast<f32x4*>(out + 1ll * n) + i);
            p.x = ax.z; p.y = ay.z; p.z = az.z; p.w = aw.z;
            __builtin_nontemporal_store(p, reinterpret_cast<f32x4*>(out + 2ll * n) + i);
            p.x = ax.w; p.y = ay.w; p.z = az.w; p.w = aw.w;
            __builtin_nontemporal_store(p, reinterpret_cast<f32x4*>(out + 3ll * n) + i);
            p.x = bx.x; p.y = by.x; p.z = bz.x; p.w = bw.x;
            __builtin_nontemporal_store(p, reinterpret_cast<f32x4*>(out + 4ll * n) + i);
            p.x = bx.y; p.y = by.y; p.z = bz.y; p.w = bw.y;
            __builtin_nontemporal_store(p, reinterpret_cast<f32x4*>(out + 5ll * n) + i);
            p.x = bx.z; p.y = by.z; p.z = bz.z; p.w = bw.z;
            __builtin_nontemporal_store(p, reinterpret_cast<f32x4*>(out + 6ll * n) + i);
            p.x = bx.w; p.y = by.w; p.z = bz.w; p.w = bw.w;
            __builtin_nontemporal_store(p, reinterpret_cast<f32x4*>(out + 7ll * n) + i);
        }
        for (int i = nv * 4 + gtid; i < n; i += gstride) {
            int s = sid[i];
            #pragma unroll
            for (int k = 0; k < 8; ++k)
                out[(long long)k * n + i] = table[8 * s + k];
        }
    }
}

// ====================== classic 5-kernel fallback path ======================
__global__ __launch_bounds__(1024) void bmax_kernel(
    const int* __restrict__ sid, const int* __restrict__ hitid,
    const float* __restrict__ beta, unsigned* __restrict__ partial,
    unsigned* __restrict__ corr_g, int n) {
    __shared__ unsigned bm[NBINS];
    for (int i = threadIdx.x; i < NBINS; i += 1024) bm[i] = 0u;
    if (blockIdx.x == 0)
        for (int i = threadIdx.x; i < NBINS; i += 1024) corr_g[i] = 0u;
    __syncthreads();
    const int tid = blockIdx.x * blockDim.x + threadIdx.x;
    const int stride = gridDim.x * blockDim.x;
    const int nv = n >> 2;
    for (int i = tid; i < nv; i += stride) {
        int4 s4 = reinterpret_cast<const int4*>(sid)[i];
        int4 h4 = reinterpret_cast<const int4*>(hitid)[i];
        float4 b4 = reinterpret_cast<const float4*>(beta)[i];
        const int* sp = (const int*)&s4;
        const int* hp = (const int*)&h4;
        const float* bp = (const float*)&b4;
        #pragma unroll
        for (int j = 0; j < 4; ++j)
            atomicMax(&bm[(hp[j] != 0 ? G_SHOWERS : 0) + sp[j]], __float_as_uint(bp[j]));
    }
    for (int i = nv * 4 + tid; i < n; i += stride)
        atomicMax(&bm[(hitid[i] != 0 ? G_SHOWERS : 0) + sid[i]], __float_as_uint(beta[i]));
    __syncthreads();
    unsigned* outp = partial + (size_t)blockIdx.x * NBINS;
    for (int i = threadIdx.x; i < NBINS; i += 1024) outp[i] = bm[i];
}

__global__ __launch_bounds__(256) void bmax_reduce(
    const unsigned* __restrict__ partial, unsigned* __restrict__ bmax_g, int nb) {
    const int qq = threadIdx.x >> 6, lane = threadIdx.x & 63;
    const int bin = blockIdx.x * 64 + lane;
    unsigned m = 0u;
    for (int b = qq; b < nb; b += 4) m = max(m, partial[(size_t)b * NBINS + bin]);
    __shared__ unsigned red[4][64];
    red[qq][lane] = m;
    __syncthreads();
    if (qq == 0)
        bmax_g[bin] = max(max(red[0][lane], red[1][lane]), max(red[2][lane], red[3][lane]));
}

__global__ __launch_bounds__(1024) void esum_corr_kernel(
    const int* __restrict__ sid, const int* __restrict__ hitid,
    const float* __restrict__ energy, const float* __restrict__ beta,
    const float* __restrict__ corr, const unsigned* __restrict__ bmax_g,
    float* __restrict__ partial_e, unsigned* __restrict__ corr_g, int n) {
    __shared__ float es[NBINS];
    for (int i = threadIdx.x; i < NBINS; i += 1024) es[i] = 0.0f;
    __syncthreads();
    const int tid = blockIdx.x * blockDim.x + threadIdx.x;
    const int stride = gridDim.x * blockDim.x;
    const int nv = n >> 2;
    for (int i = tid; i < nv; i += stride) {
        int4 s4 = reinterpret_cast<const int4*>(sid)[i];
        int4 h4 = reinterpret_cast<const int4*>(hitid)[i];
        float4 e4 = reinterpret_cast<const float4*>(energy)[i];
        float4 b4 = reinterpret_cast<const float4*>(beta)[i];
        float4 c4 = reinterpret_cast<const float4*>(corr)[i];
        const int* sp = (const int*)&s4;
        const int* hp = (const int*)&h4;
        const float* ep = (const float*)&e4;
        const float* bp = (const float*)&b4;
        const float* cp = (const float*)&c4;
        #pragma unroll
        for (int j = 0; j < 4; ++j) {
            int bin = (hp[j] != 0 ? G_SHOWERS : 0) + sp[j];
            atomicAdd(&es[bin], ep[j]);
            if (__float_as_uint(bp[j]) == __ldg(&bmax_g[bin]))
                atomicMax(&corr_g[bin], __float_as_uint(cp[j]));
        }
    }
    for (int i = nv * 4 + tid; i < n; i += stride) {
        int bin = (hitid[i] != 0 ? G_SHOWERS : 0) + sid[i];
        atomicAdd(&es[bin], energy[i]);
        if (__float_as_uint(beta[i]) == __ldg(&bmax_g[bin]))
            atomicMax(&corr_g[bin], __float_as_uint(corr[i]));
    }
    __syncthreads();
    float* outp = partial_e + (size_t)blockIdx.x * NBINS;
    for (int i = threadIdx.x; i < NBINS; i += 1024) outp[i] = es[i];
}

__global__ __launch_bounds__(256) void table_kernel(
    const float* __restrict__ partial_e, const unsigned* __restrict__ corr_g,
    float* __restrict__ table, int nb) {
    const int qq = threadIdx.x >> 6, lane = threadIdx.x & 63;
    const int g = blockIdx.x * 64 + lane;
    float ah = 0.0f, at = 0.0f;
    for (int b = qq; b < nb; b += 4) {
        const float* p = partial_e + (size_t)b * NBINS;
        ah += p[g];
        at += p[G_SHOWERS + g];
    }
    __shared__ float rh[4][64], rt[4][64];
    rh[qq][lane] = ah;
    rt[qq][lane] = at;
    __syncthreads();
    if (qq == 0) {
        float raw_hit = rh[0][lane] + rh[1][lane] + rh[2][lane] + rh[3][lane];
        float raw_trk = rt[0][lane] + rt[1][lane] + rt[2][lane] + rt[3][lane];
        float cor_hit = __uint_as_float(corr_g[g]) * raw_hit;
        float cor_trk = __uint_as_float(corr_g[G_SHOWERS + g]) * raw_trk;
        float4 lo, hi;
        lo.x = raw_trk; lo.y = cor_trk; lo.z = raw_hit; lo.w = cor_hit;
        hi.x = (raw_trk != 0.0f) ? raw_trk : raw_hit;
        hi.y = (cor_trk != 0.0f) ? cor_trk : cor_hit;
        hi.z = (raw_hit != 0.0f) ? raw_hit : raw_trk;
        hi.w = (cor_hit != 0.0f) ? cor_hit : cor_trk;
        reinterpret_cast<float4*>(table)[2 * g]     = lo;
        reinterpret_cast<float4*>(table)[2 * g + 1] = hi;
    }
}

__global__ void gather_kernel(const int* __restrict__ sid,
                              const float* __restrict__ table,
                              float* __restrict__ out, int n) {
    const int tid = blockIdx.x * blockDim.x + threadIdx.x;
    const int stride = gridDim.x * blockDim.x;
    const int nv = n >> 2;
    const f32x4* tbl = reinterpret_cast<const f32x4*>(table);
    for (int i = tid; i < nv; i += stride) {
        int4 s4 = reinterpret_cast<const int4*>(sid)[i];
        f32x4 ax = tbl[2 * s4.x], bx = tbl[2 * s4.x + 1];
        f32x4 ay = tbl[2 * s4.y], by = tbl[2 * s4.y + 1];
        f32x4 az = tbl[2 * s4.z], bz = tbl[2 * s4.z + 1];
        f32x4 aw = tbl[2 * s4.w], bw = tbl[2 * s4.w + 1];
        f32x4 p;
        p.x = ax.x; p.y = ay.x; p.z = az.x; p.w = aw.x;
        __builtin_nontemporal_store(p, reinterpret_cast<f32x4*>(out + 0ll * n) + i);
        p.x = ax.y; p.y = ay.y; p.z = az.y; p.w = aw.y;
        __builtin_nontemporal_store(p, reinterpret_cast<f32x4*>(out + 1ll * n) + i);
        p.x = ax.z; p.y = ay.z; p.z = az.z; p.w = aw.z;
        __builtin_nontemporal_store(p, reinterpret_cast<f32x4*>(out + 2ll * n) + i);
        p.x = ax.w; p.y = ay.w; p.z = az.w; p.w = aw.w;
        __builtin_nontemporal_store(p, reinterpret_cast<f32x4*>(out + 3ll * n) + i);
        p.x = bx.x; p.y = by.x; p.z = bz.x; p.w = bw.x;
        __builtin_nontemporal_store(p, reinterpret_cast<f32x4*>(out + 4ll * n) + i);
        p.x = bx.y; p.y = by.y; p.z = bz.y; p.w = bw.y;
        __builtin_nontemporal_store(p, reinterpret_cast<f32x4*>(out + 5ll * n) + i);
        p.x = bx.z; p.y = by.z; p.z = bz.z; p.w = bw.z;
        __builtin_nontemporal_store(p, reinterpret_cast<f32x4*>(out + 6ll * n) + i);
        p.x = bx.w; p.y = by.w; p.z = bz.w; p.w = bw.w;
        __builtin_nontemporal_store(p, reinterpret_cast<f32x4*>(out + 7ll * n) + i);
    }
    for (int i = nv * 4 + tid; i < n; i += stride) {
        int s = sid[i];
        #pragma unroll
        for (int k = 0; k < 8; ++k)
            out[(long long)k * n + i] = table[8 * s + k];
    }
}

extern "C" void kernel_launch(void* const* d_in, const int* in_sizes, int n_in,
                              void* d_out, int out_size, void* d_ws, size_t ws_size,
                              hipStream_t stream) {
    const int*   sid    = (const int*)d_in[0];
    const int*   hitid  = (const int*)d_in[1];
    const float* energy = (const float*)d_in[2];
    const float* beta   = (const float*)d_in[3];
    const float* corr   = (const float*)d_in[4];
    int n = in_sizes[0];
    float* outp = (float*)d_out;

    const size_t slab_bytes = (size_t)NBINS * 4;  // 64 KB
    const size_t fixed_bytes = 6 * slab_bytes;    // bmax_g + corr_g + table
    int nb = 256;
    if (ws_size < (size_t)nb * slab_bytes + fixed_bytes) {
        size_t avail = (ws_size > fixed_bytes) ? (ws_size - fixed_bytes) : slab_bytes;
        nb = (int)(avail / slab_bytes) & ~3;
        if (nb < 8) nb = 8;
        if (nb > 256) nb = 256;
    }

    char* base = (char*)d_ws;
    unsigned* partial = (unsigned*)base;
    unsigned* bmax_g  = (unsigned*)(base + (size_t)nb * slab_bytes);
    unsigned* corr_g  = (unsigned*)((char*)bmax_g + slab_bytes);
    float*    table   = (float*)((char*)corr_g + slab_bytes);
    // optional bin stash after table (table = 4 slabs worth = 256 KB)
    size_t used = (size_t)nb * slab_bytes + fixed_bytes;
    size_t bin_bytes = ((size_t)n * 2 + 255) & ~(size_t)255;
    unsigned short* binbuf = nullptr;
    if (ws_size >= used + bin_bytes)
        binbuf = (unsigned short*)(base + used);

    // ---- try fused cooperative launch ----
    void* args[] = {(void*)&sid, (void*)&hitid, (void*)&energy, (void*)&beta,
                    (void*)&corr, (void*)&partial, (void*)&bmax_g, (void*)&corr_g,
                    (void*)&table, (void*)&binbuf, (void*)&outp, (void*)&n,
                    (void*)&nb};
    hipError_t err = hipLaunchCooperativeKernel((const void*)fused_kernel,
                                                dim3(nb), dim3(1024), args, 0,
                                                stream);
    if (err == hipSuccess) return;
    (void)hipGetLastError();  // clear error, fall back to classic path

    bmax_kernel<<<nb, 1024, 0, stream>>>(sid, hitid, beta, partial, corr_g, n);
    bmax_reduce<<<NBINS / 64, 256, 0, stream>>>(partial, bmax_g, nb);
    esum_corr_kernel<<<nb, 1024, 0, stream>>>(sid, hitid, energy, beta, corr,
                                              bmax_g, (float*)partial, corr_g, n);
    table_kernel<<<G_SHOWERS / 64, 256, 0, stream>>>((float*)partial, corr_g, table, nb);
    gather_kernel<<<2048, 256, 0, stream>>>(sid, table, outp, n);
}

// Round 6
// 86.446 us; speedup vs baseline: 2.5850x; 2.5850x over previous
//
#include <hip/hip_runtime.h>
#include <stdint.h>

#define G_SHOWERS 8192
#define NBINS (2 * G_SHOWERS)  // bin = kind*8192 + sid; kind: 0=hits, 1=tracks

typedef float f32x4 __attribute__((ext_vector_type(4)));

// ws layout (nb slabs, slab region reused by both element passes):
//   [0, nb*64K)   : partial slabs u32/f32 [nb][NBINS]
//   [+0,   +64K)  : bmax_g u32[NBINS]
//   [+64K, +128K) : corr_g u32[NBINS]   (zeroed by bmax_kernel block 0)
//   [+128K,+384K) : table  f32[G][8]
//   [+384K, ...)  : binbuf u16[n] (optional, if ws large enough)

// ---- K1: per-block beta-max partials in LDS + bin stash; blk0 zeroes corr_g
__global__ __launch_bounds__(1024) void bmax_kernel(
    const int* __restrict__ sid, const int* __restrict__ hitid,
    const float* __restrict__ beta, unsigned* __restrict__ partial,
    unsigned* __restrict__ corr_g, unsigned short* __restrict__ binbuf, int n) {
    __shared__ unsigned bm[NBINS];
    for (int i = threadIdx.x; i < NBINS; i += 1024) bm[i] = 0u;
    if (blockIdx.x == 0)
        for (int i = threadIdx.x; i < NBINS; i += 1024) corr_g[i] = 0u;
    __syncthreads();

    const int tid = blockIdx.x * blockDim.x + threadIdx.x;
    const int stride = gridDim.x * blockDim.x;
    const int nv = n >> 2;
    for (int i = tid; i < nv; i += stride) {
        int4   s4 = reinterpret_cast<const int4*>(sid)[i];
        int4   h4 = reinterpret_cast<const int4*>(hitid)[i];
        float4 b4 = reinterpret_cast<const float4*>(beta)[i];
        const int* sp = (const int*)&s4;
        const int* hp = (const int*)&h4;
        const float* bp = (const float*)&b4;
        ushort4 bv;
        unsigned short* bvp = (unsigned short*)&bv;
        #pragma unroll
        for (int j = 0; j < 4; ++j) {
            int bin = (hp[j] != 0 ? G_SHOWERS : 0) + sp[j];
            bvp[j] = (unsigned short)bin;
            atomicMax(&bm[bin], __float_as_uint(bp[j]));
        }
        if (binbuf) reinterpret_cast<ushort4*>(binbuf)[i] = bv;
    }
    for (int i = nv * 4 + tid; i < n; i += stride) {
        int bin = (hitid[i] != 0 ? G_SHOWERS : 0) + sid[i];
        if (binbuf) binbuf[i] = (unsigned short)bin;
        atomicMax(&bm[bin], __float_as_uint(beta[i]));
    }

    __syncthreads();
    unsigned* outp = partial + (size_t)blockIdx.x * NBINS;
    for (int i = threadIdx.x; i < NBINS; i += 1024) outp[i] = bm[i];
}

// ---- R1: reduce bmax partials, 4 quarter-chains per bin, coalesced ---------
__global__ __launch_bounds__(256) void bmax_reduce(
    const unsigned* __restrict__ partial, unsigned* __restrict__ bmax_g, int nb) {
    const int q = threadIdx.x >> 6, lane = threadIdx.x & 63;
    const int bin = blockIdx.x * 64 + lane;
    unsigned m = 0u;
    #pragma unroll 8
    for (int b = q; b < nb; b += 4)
        m = max(m, partial[(size_t)b * NBINS + bin]);
    __shared__ unsigned red[4][64];
    red[q][lane] = m;
    __syncthreads();
    if (q == 0)
        bmax_g[bin] = max(max(red[0][lane], red[1][lane]),
                          max(red[2][lane], red[3][lane]));
}

// ---- K3: esum partials in LDS + sparse corr atomicMax ----------------------
__global__ __launch_bounds__(1024) void esum_corr_kernel(
    const int* __restrict__ sid, const int* __restrict__ hitid,
    const float* __restrict__ energy, const float* __restrict__ beta,
    const float* __restrict__ corr, const unsigned* __restrict__ bmax_g,
    float* __restrict__ partial_e, unsigned* __restrict__ corr_g,
    const unsigned short* __restrict__ binbuf, int n) {
    __shared__ float es[NBINS];
    for (int i = threadIdx.x; i < NBINS; i += 1024) es[i] = 0.0f;
    __syncthreads();

    const int tid = blockIdx.x * blockDim.x + threadIdx.x;
    const int stride = gridDim.x * blockDim.x;
    const int nv = n >> 2;
    for (int i = tid; i < nv; i += stride) {
        float4 e4 = reinterpret_cast<const float4*>(energy)[i];
        float4 b4 = reinterpret_cast<const float4*>(beta)[i];
        float4 c4 = reinterpret_cast<const float4*>(corr)[i];
        const float* ep = (const float*)&e4;
        const float* bp = (const float*)&b4;
        const float* cp = (const float*)&c4;
        int bins[4];
        if (binbuf) {
            ushort4 bv = reinterpret_cast<const ushort4*>(binbuf)[i];
            bins[0] = bv.x; bins[1] = bv.y; bins[2] = bv.z; bins[3] = bv.w;
        } else {
            int4 s4 = reinterpret_cast<const int4*>(sid)[i];
            int4 h4 = reinterpret_cast<const int4*>(hitid)[i];
            const int* sp = (const int*)&s4;
            const int* hp = (const int*)&h4;
            #pragma unroll
            for (int j = 0; j < 4; ++j)
                bins[j] = (hp[j] != 0 ? G_SHOWERS : 0) + sp[j];
        }
        #pragma unroll
        for (int j = 0; j < 4; ++j) {
            atomicAdd(&es[bins[j]], ep[j]);
            if (__float_as_uint(bp[j]) == __ldg(&bmax_g[bins[j]]))
                atomicMax(&corr_g[bins[j]], __float_as_uint(cp[j]));  // ~16K total
        }
    }
    for (int i = nv * 4 + tid; i < n; i += stride) {
        int bin = (hitid[i] != 0 ? G_SHOWERS : 0) + sid[i];
        atomicAdd(&es[bin], energy[i]);
        if (__float_as_uint(beta[i]) == __ldg(&bmax_g[bin]))
            atomicMax(&corr_g[bin], __float_as_uint(corr[i]));
    }

    __syncthreads();
    float* outp = partial_e + (size_t)blockIdx.x * NBINS;
    for (int i = threadIdx.x; i < NBINS; i += 1024) outp[i] = es[i];
}

// ---- T: reduce esum partials (4 chains/shower, coalesced) + build table ----
__global__ __launch_bounds__(256) void table_kernel(
    const float* __restrict__ partial_e, const unsigned* __restrict__ corr_g,
    float* __restrict__ table, int nb) {
    const int q = threadIdx.x >> 6, lane = threadIdx.x & 63;
    const int g = blockIdx.x * 64 + lane;
    float ah = 0.0f, at = 0.0f;
    #pragma unroll 8
    for (int b = q; b < nb; b += 4) {
        const float* p = partial_e + (size_t)b * NBINS;
        ah += p[g];
        at += p[G_SHOWERS + g];
    }
    __shared__ float rh[4][64], rt[4][64];
    rh[q][lane] = ah;
    rt[q][lane] = at;
    __syncthreads();
    if (q == 0) {
        float raw_hit = rh[0][lane] + rh[1][lane] + rh[2][lane] + rh[3][lane];
        float raw_trk = rt[0][lane] + rt[1][lane] + rt[2][lane] + rt[3][lane];
        float cor_hit = __uint_as_float(corr_g[g]) * raw_hit;
        float cor_trk = __uint_as_float(corr_g[G_SHOWERS + g]) * raw_trk;
        float4 lo, hi;
        lo.x = raw_trk; lo.y = cor_trk; lo.z = raw_hit; lo.w = cor_hit;
        hi.x = (raw_trk != 0.0f) ? raw_trk : raw_hit;
        hi.y = (cor_trk != 0.0f) ? cor_trk : cor_hit;
        hi.z = (raw_hit != 0.0f) ? raw_hit : raw_trk;
        hi.w = (cor_hit != 0.0f) ? cor_hit : cor_trk;
        reinterpret_cast<float4*>(table)[2 * g]     = lo;
        reinterpret_cast<float4*>(table)[2 * g + 1] = hi;
    }
}

// ---- G: broadcast gather to 8 output planes (nontemporal stores) -----------
__global__ __launch_bounds__(256) void gather_kernel(
    const int* __restrict__ sid, const unsigned short* __restrict__ binbuf,
    const float* __restrict__ table, float* __restrict__ out, int n) {
    const int tid = blockIdx.x * blockDim.x + threadIdx.x;
    const int stride = gridDim.x * blockDim.x;
    const int nv = n >> 2;
    const f32x4* tbl = reinterpret_cast<const f32x4*>(table);

    for (int i = tid; i < nv; i += stride) {
        int s0, s1, s2, s3;
        if (binbuf) {
            ushort4 bv = reinterpret_cast<const ushort4*>(binbuf)[i];
            s0 = bv.x & (G_SHOWERS - 1); s1 = bv.y & (G_SHOWERS - 1);
            s2 = bv.z & (G_SHOWERS - 1); s3 = bv.w & (G_SHOWERS - 1);
        } else {
            int4 s4 = reinterpret_cast<const int4*>(sid)[i];
            s0 = s4.x; s1 = s4.y; s2 = s4.z; s3 = s4.w;
        }
        f32x4 ax = tbl[2 * s0], bx = tbl[2 * s0 + 1];
        f32x4 ay = tbl[2 * s1], by = tbl[2 * s1 + 1];
        f32x4 az = tbl[2 * s2], bz = tbl[2 * s2 + 1];
        f32x4 aw = tbl[2 * s3], bw = tbl[2 * s3 + 1];

        f32x4 p;
        p.x = ax.x; p.y = ay.x; p.z = az.x; p.w = aw.x;
        __builtin_nontemporal_store(p, reinterpret_cast<f32x4*>(out + 0ll * n) + i);
        p.x = ax.y; p.y = ay.y; p.z = az.y; p.w = aw.y;
        __builtin_nontemporal_store(p, reinterpret_cast<f32x4*>(out + 1ll * n) + i);
        p.x = ax.z; p.y = ay.z; p.z = az.z; p.w = aw.z;
        __builtin_nontemporal_store(p, reinterpret_cast<f32x4*>(out + 2ll * n) + i);
        p.x = ax.w; p.y = ay.w; p.z = az.w; p.w = aw.w;
        __builtin_nontemporal_store(p, reinterpret_cast<f32x4*>(out + 3ll * n) + i);
        p.x = bx.x; p.y = by.x; p.z = bz.x; p.w = bw.x;
        __builtin_nontemporal_store(p, reinterpret_cast<f32x4*>(out + 4ll * n) + i);
        p.x = bx.y; p.y = by.y; p.z = bz.y; p.w = bw.y;
        __builtin_nontemporal_store(p, reinterpret_cast<f32x4*>(out + 5ll * n) + i);
        p.x = bx.z; p.y = by.z; p.z = bz.z; p.w = bw.z;
        __builtin_nontemporal_store(p, reinterpret_cast<f32x4*>(out + 6ll * n) + i);
        p.x = bx.w; p.y = by.w; p.z = bz.w; p.w = bw.w;
        __builtin_nontemporal_store(p, reinterpret_cast<f32x4*>(out + 7ll * n) + i);
    }
    for (int i = nv * 4 + tid; i < n; i += stride) {
        int s = sid[i];
        #pragma unroll
        for (int k = 0; k < 8; ++k)
            out[(long long)k * n + i] = table[8 * s + k];
    }
}

extern "C" void kernel_launch(void* const* d_in, const int* in_sizes, int n_in,
                              void* d_out, int out_size, void* d_ws, size_t ws_size,
                              hipStream_t stream) {
    const int*   sid    = (const int*)d_in[0];
    const int*   hitid  = (const int*)d_in[1];
    const float* energy = (const float*)d_in[2];
    const float* beta   = (const float*)d_in[3];
    const float* corr   = (const float*)d_in[4];
    const int n = in_sizes[0];

    const size_t slab_bytes = (size_t)NBINS * 4;  // 64 KB
    const size_t fixed_bytes = 6 * slab_bytes;    // bmax_g + corr_g + table
    int nb = 256;
    if (ws_size < (size_t)nb * slab_bytes + fixed_bytes) {
        size_t avail = (ws_size > fixed_bytes) ? (ws_size - fixed_bytes) : slab_bytes;
        nb = (int)(avail / slab_bytes) & ~3;
        if (nb < 8) nb = 8;
        if (nb > 256) nb = 256;
    }

    char* base = (char*)d_ws;
    unsigned* partial = (unsigned*)base;   // slab region reused by both passes
    unsigned* bmax_g  = (unsigned*)(base + (size_t)nb * slab_bytes);
    unsigned* corr_g  = (unsigned*)((char*)bmax_g + slab_bytes);
    float*    table   = (float*)((char*)corr_g + slab_bytes);

    size_t used = (size_t)nb * slab_bytes + fixed_bytes;
    size_t bin_bytes = ((size_t)n * 2 + 255) & ~(size_t)255;
    unsigned short* binbuf = nullptr;
    if (ws_size >= used + bin_bytes)
        binbuf = (unsigned short*)(base + used);

    bmax_kernel<<<nb, 1024, 0, stream>>>(sid, hitid, beta, partial, corr_g,
                                         binbuf, n);
    bmax_reduce<<<NBINS / 64, 256, 0, stream>>>(partial, bmax_g, nb);
    esum_corr_kernel<<<nb, 1024, 0, stream>>>(sid, hitid, energy, beta, corr,
                                              bmax_g, (float*)partial, corr_g,
                                              binbuf, n);
    table_kernel<<<G_SHOWERS / 64, 256, 0, stream>>>((float*)partial, corr_g,
                                                     table, nb);
    gather_kernel<<<4096, 256, 0, stream>>>(sid, binbuf, table, (float*)d_out, n);
}